// Round 21
// baseline (269.303 us; speedup 1.0000x reference)
//
#include <hip/hip_runtime.h>
#include <hip/hip_fp16.h>
#include <hip/hip_bf16.h>

// PGNN layer for MI355X (gfx950).
//   u = feature @ W_u + b_u ; v = feature @ W_v + b_v       [N,64] each
//   msg[e] = v[dst[e]] + u[src[e]] * sp_dist[e]
//   msgs = relu(msg[anchor_eid]) -> [N,K,64]
//   out_position = msgs @ W_out + b_out  [N,K];  out_structure = mean_k [N,64]
// N=50000, K=64, E=3.2M. d_out = out_position ++ out_structure.
//
// R21 vs R20 (evidence: inline meta-gather in pass0 = 110us fetch-bound,
// meta thrash evicts the L2 slice -> pack must stay a separate phase.
// R16/R19 segregated block ranges = zero overlap: 1024 slots, 1024 pack
// blocks first -> proj queues behind):
//   fused kernel with ROLE-INTERLEAVED blocks: grid 1042, idx%4==3 -> pack
//   (260 blocks), else proj (782). Both roles co-resident from t=0; pack
//   saturates fabric, proj the VALU. Passes read packed coalesced (R16);
//   pass0 plain-stores pos+b_out (no init kernel). Merge standalone first.

#define IN_DIM 256
#define OUT_DIM 64
#define KANCH 64

typedef float vfloat4 __attribute__((ext_vector_type(4)));
typedef float vfloat2 __attribute__((ext_vector_type(2)));

// ---------------- merge: (src,dst,sp16) -> meta[E] 8B ----------------------
__global__ __launch_bounds__(256) void pgnn_merge_kernel(
    const int* __restrict__ src, const int* __restrict__ dst,
    const float* __restrict__ sp, unsigned long long* __restrict__ meta, int E)
{
    int i = blockIdx.x * 256 + threadIdx.x;
    if (i >= E) return;
    unsigned long long pk =
          (unsigned long long)(unsigned)__builtin_nontemporal_load(&src[i])
        | ((unsigned long long)(unsigned)__builtin_nontemporal_load(&dst[i]) << 17)
        | ((unsigned long long)__half_as_ushort(
               __float2half_rn(__builtin_nontemporal_load(&sp[i]))) << 34);
    __builtin_nontemporal_store(pk, &meta[i]);
}

// ---------------- fused: proj GEMM (dbuf) + pack, role-interleaved ---------
// role: blockIdx%4==3 -> pack block (pack_id = blockIdx>>2, packBlocks total)
//       else          -> proj block (proj_id = blockIdx - (blockIdx+1)/4)
//   uq8 [2][N][32]  fp8 e4m3 u (slice q: dims 32q..+31)
//   vh16[2][N][32]  fp16     v (slice q: dims 32q..+31)
#define PAa 68
#define PBb 132
#define TILEF (16 * PAa + 16 * PBb)   // floats per buffer = 3200
__global__ __launch_bounds__(256) void pgnn_front_kernel(
    const float* __restrict__ feature,
    const float* __restrict__ Wu, const float* __restrict__ bu,
    const float* __restrict__ Wv, const float* __restrict__ bv,
    unsigned char* __restrict__ uq8,
    __half* __restrict__ vh16,
    const int* __restrict__ aeid,
    const unsigned long long* __restrict__ meta,
    unsigned long long* __restrict__ packed,
    int N, int M, int projBlocks, int packBlocks)
{
    __shared__ float smem[2 * TILEF];
    const int tid = threadIdx.x;
    const int bidx = (int)blockIdx.x;

    const bool isPack = packBlocks > 0 && (bidx & 3) == 3;
    if (isPack) {
        // ---------------- pack body (batched x8 grid-stride) ----------------
        const int pack_id = bidx >> 2;
        const int stride = packBlocks * 256;
        int i = pack_id * 256 + tid;
        while (i + 7 * stride < M) {
            int e[8];
            #pragma unroll
            for (int b = 0; b < 8; ++b)
                e[b] = __builtin_nontemporal_load(&aeid[i + b * stride]);
            unsigned long long m[8];
            #pragma unroll
            for (int b = 0; b < 8; ++b) m[b] = meta[e[b]];   // PLAIN (L2/L3)
            #pragma unroll
            for (int b = 0; b < 8; ++b)
                __builtin_nontemporal_store(m[b], &packed[i + b * stride]);
            i += 8 * stride;
        }
        for (; i < M; i += stride) {
            int e = __builtin_nontemporal_load(&aeid[i]);
            __builtin_nontemporal_store(meta[e], &packed[i]);
        }
        return;
    }

    // ---------------- proj body (double-buffered) ----------------
    const int proj_id = packBlocks > 0 ? bidx - ((bidx + 1) >> 2) : bidx;
    if (proj_id >= projBlocks) return;
    const int row0 = proj_id * 64;
    const int tr = tid >> 4;     // 0..15 -> rows tr*4..+3
    const int tc = tid & 15;     // 0..15 -> col quads (u: tc*4, v: 64+tc*4)
    const int mA = tid >> 2, c4A = tid & 3;
    const int grA = row0 + mA;

    float accU[4][4], accV[4][4];
    #pragma unroll
    for (int i = 0; i < 4; ++i)
        #pragma unroll
        for (int j = 0; j < 4; ++j) { accU[i][j] = 0.f; accV[i][j] = 0.f; }

    float4 ra, rb0, rb1;
    auto load_tile = [&](int k0) {
        ra = make_float4(0.f, 0.f, 0.f, 0.f);
        if (grA < N)
            ra = *reinterpret_cast<const float4*>(
                    &feature[(size_t)grA * IN_DIM + k0 + c4A * 4]);
        {
            int f = tid, kk = f >> 5, c4 = f & 31;
            rb0 = (c4 < 16)
                ? *reinterpret_cast<const float4*>(&Wu[(k0 + kk) * OUT_DIM + c4 * 4])
                : *reinterpret_cast<const float4*>(&Wv[(k0 + kk) * OUT_DIM + (c4 - 16) * 4]);
        }
        {
            int f = tid + 256, kk = f >> 5, c4 = f & 31;
            rb1 = (c4 < 16)
                ? *reinterpret_cast<const float4*>(&Wu[(k0 + kk) * OUT_DIM + c4 * 4])
                : *reinterpret_cast<const float4*>(&Wv[(k0 + kk) * OUT_DIM + (c4 - 16) * 4]);
        }
    };
    auto store_tile = [&](float* buf) {
        buf[(c4A * 4 + 0) * PAa + mA] = ra.x;
        buf[(c4A * 4 + 1) * PAa + mA] = ra.y;
        buf[(c4A * 4 + 2) * PAa + mA] = ra.z;
        buf[(c4A * 4 + 3) * PAa + mA] = ra.w;
        float* sB = buf + 16 * PAa;
        {
            int f = tid, kk = f >> 5, c4 = f & 31;
            *reinterpret_cast<float4*>(&sB[kk * PBb + c4 * 4]) = rb0;
        }
        {
            int f = tid + 256, kk = f >> 5, c4 = f & 31;
            *reinterpret_cast<float4*>(&sB[kk * PBb + c4 * 4]) = rb1;
        }
    };

    load_tile(0);
    store_tile(smem);
    __syncthreads();

    for (int s = 0; s < 16; ++s) {
        const int cur = s & 1;
        if (s < 15) load_tile((s + 1) * 16);
        const float* buf = smem + cur * TILEF;
        const float* sB  = buf + 16 * PAa;
        #pragma unroll
        for (int k = 0; k < 16; ++k) {
            float4 a  = *reinterpret_cast<const float4*>(&buf[k * PAa + tr * 4]);
            float4 b0 = *reinterpret_cast<const float4*>(&sB[k * PBb + tc * 4]);
            float4 b1 = *reinterpret_cast<const float4*>(&sB[k * PBb + 64 + tc * 4]);
            float av[4]  = {a.x, a.y, a.z, a.w};
            float bu4[4] = {b0.x, b0.y, b0.z, b0.w};
            float bv4[4] = {b1.x, b1.y, b1.z, b1.w};
            #pragma unroll
            for (int i = 0; i < 4; ++i)
                #pragma unroll
                for (int j = 0; j < 4; ++j) {
                    accU[i][j] = fmaf(av[i], bu4[j], accU[i][j]);
                    accV[i][j] = fmaf(av[i], bv4[j], accV[i][j]);
                }
        }
        if (s < 15) store_tile(smem + (cur ^ 1) * TILEF);
        __syncthreads();
    }

    // Epilogue: bias; u -> fp8 (HW pack), v -> fp16. Slice qs = tc>>3.
    const int qs   = tc >> 3;
    const int offq = (tc & 7) * 4;     // dim offset within 32-dim slice
    float bU[4], bV[4];
    #pragma unroll
    for (int j = 0; j < 4; ++j) { bU[j] = bu[tc * 4 + j]; bV[j] = bv[tc * 4 + j]; }
    #pragma unroll
    for (int i = 0; i < 4; ++i) {
        int gr = row0 + tr * 4 + i;
        if (gr >= N) continue;
        unsigned char* urow = uq8 + ((size_t)qs * N + gr) * 32;
        int pu = 0;
        pu = __builtin_amdgcn_cvt_pk_fp8_f32(accU[i][0] + bU[0],
                                             accU[i][1] + bU[1], pu, false);
        pu = __builtin_amdgcn_cvt_pk_fp8_f32(accU[i][2] + bU[2],
                                             accU[i][3] + bU[3], pu, true);
        *reinterpret_cast<unsigned int*>(urow + offq) = (unsigned)pu;

        __half* vrow = vh16 + ((size_t)qs * N + gr) * 32;
        __half2 hv0 = __floats2half2_rn(accV[i][0] + bV[0], accV[i][1] + bV[1]);
        __half2 hv1 = __floats2half2_rn(accV[i][2] + bV[2], accV[i][3] + bV[3]);
        *reinterpret_cast<__half2*>(vrow + offq)     = hv0;
        *reinterpret_cast<__half2*>(vrow + offq + 2) = hv1;
    }
}

// ---------------- edge pass (u fp8 + v fp16, one slice q) ------------------
// One wave per node, 4 waves/block. lane = (g = lane>>2, j = lane&3).
// Anchor k = i*16+g (i=0..3): u = 8B fp8 octet of row ss, v = 16B fp16 octet
// of row dd. META: 0 = read packed (coalesced), 2 = raw gather (fallback).
// FIRST: plain-store pos + b_out (else atomicAdd).
template<int META, bool FIRST>
__global__ __launch_bounds__(256) void pgnn_pass_kernel(
    const unsigned char* __restrict__ uq8,
    const __half* __restrict__ vh16,
    const int*    __restrict__ src,
    const int*    __restrict__ dst,
    const float*  __restrict__ sp_dist,
    const int*    __restrict__ aeid,
    const unsigned long long* __restrict__ packed,
    const float*  __restrict__ W_out,
    const float*  __restrict__ b_out,
    float* __restrict__ out_pos,     // [N,64]
    float* __restrict__ out_struct,  // [N,64]
    int N, int q)
{
    const int lane = threadIdx.x & 63;
    const int wv   = threadIdx.x >> 6;
    const int n    = blockIdx.x * 4 + wv;
    if (n >= N) return;   // wave-uniform

    __shared__ float posb[4][64];
    float* pb = posb[wv];

    const int j = lane & 3, g = lane >> 2;

    int ms, md; float msp;
    if constexpr (META == 2) {
        const int e = __builtin_nontemporal_load(&aeid[(size_t)n * KANCH + lane]);
        ms = src[e]; md = dst[e]; msp = sp_dist[e];
    } else {
        unsigned long long pk =
            __builtin_nontemporal_load(&packed[(size_t)n * KANCH + lane]);
        unsigned lo = (unsigned)pk, hi = (unsigned)(pk >> 32);
        ms = (int)(lo & 0x1FFFFu);
        md = (int)(((lo >> 17) | (hi << 15)) & 0x1FFFFu);
        msp = __half2float(__ushort_as_half((unsigned short)((hi >> 2) & 0xFFFFu)));
    }

    // W_out dims q*32 + j*8 .. +7
    float w[8];
    {
        const float* Wq = &W_out[q * 32 + j * 8];
        float4 w0 = *reinterpret_cast<const float4*>(Wq);
        float4 w1 = *reinterpret_cast<const float4*>(Wq + 4);
        w[0] = w0.x; w[1] = w0.y; w[2] = w0.z; w[3] = w0.w;
        w[4] = w1.x; w[5] = w1.y; w[6] = w1.z; w[7] = w1.w;
    }

    const unsigned char* Uq = uq8  + (size_t)q * N * 32;
    const __half*        Vq = vh16 + (size_t)q * N * 32;

    float sacc[8];
    #pragma unroll
    for (int jj = 0; jj < 8; ++jj) sacc[jj] = 0.f;

    #pragma unroll
    for (int i = 0; i < 4; ++i) {
        const int k = i * 16 + g;
        const int   ss = __shfl(ms, k);
        const int   dd = __shfl(md, k);
        const float sp = __shfl(msp, k);

        uint2 uu = *reinterpret_cast<const uint2*>(Uq + (size_t)ss * 32 + j * 8);
        uint4 vv = *reinterpret_cast<const uint4*>(
                       reinterpret_cast<const unsigned char*>(Vq) +
                       (size_t)dd * 64 + j * 16);

        float uf[8], vf[8];
        {
            vfloat2 a0 = __builtin_amdgcn_cvt_pk_f32_fp8((int)uu.x, false);
            vfloat2 a1 = __builtin_amdgcn_cvt_pk_f32_fp8((int)uu.x, true);
            vfloat2 a2 = __builtin_amdgcn_cvt_pk_f32_fp8((int)uu.y, false);
            vfloat2 a3 = __builtin_amdgcn_cvt_pk_f32_fp8((int)uu.y, true);
            uf[0] = a0.x; uf[1] = a0.y; uf[2] = a1.x; uf[3] = a1.y;
            uf[4] = a2.x; uf[5] = a2.y; uf[6] = a3.x; uf[7] = a3.y;
        }
        {
            const unsigned* vp = &vv.x;
            #pragma unroll
            for (int t = 0; t < 4; ++t) {
                __half2 h2 = *reinterpret_cast<const __half2*>(&vp[t]);
                float2 f2 = __half22float2(h2);
                vf[2 * t] = f2.x; vf[2 * t + 1] = f2.y;
            }
        }

        float m[8];
        #pragma unroll
        for (int jj = 0; jj < 8; ++jj) {
            m[jj] = fmaxf(fmaf(uf[jj], sp, vf[jj]), 0.f);
            sacc[jj] += m[jj];
        }

        float p = 0.f;
        #pragma unroll
        for (int jj = 0; jj < 8; ++jj) p = fmaf(m[jj], w[jj], p);
        p += __shfl_xor(p, 1);
        p += __shfl_xor(p, 2);          // sum over the 4-lane quad
        if (j == 0) pb[k] = p;
    }
    asm volatile("s_waitcnt lgkmcnt(0)" ::: "memory");

    if constexpr (FIRST) {
        out_pos[(size_t)n * KANCH + lane] = pb[lane] + b_out[0];
    } else {
        atomicAdd(&out_pos[(size_t)n * KANCH + lane], pb[lane]);
    }

    // struct: reduce sacc over the 16 g-groups (lane bits 2..5).
    #pragma unroll
    for (int off = 4; off <= 32; off <<= 1)
        #pragma unroll
        for (int jj = 0; jj < 8; ++jj)
            sacc[jj] += __shfl_xor(sacc[jj], off);

    if (lane < 4) {   // lane j holds dims q*32 + j*8 .. +7
        const float r = 1.f / (float)KANCH;
        float* op = &out_struct[(size_t)n * OUT_DIM + q * 32 + lane * 8];
        vfloat4 s0 = { sacc[0] * r, sacc[1] * r, sacc[2] * r, sacc[3] * r };
        vfloat4 s1 = { sacc[4] * r, sacc[5] * r, sacc[6] * r, sacc[7] * r };
        __builtin_nontemporal_store(s0, reinterpret_cast<vfloat4*>(op));
        __builtin_nontemporal_store(s1, reinterpret_cast<vfloat4*>(op + 4));
    }
}

extern "C" void kernel_launch(void* const* d_in, const int* in_sizes, int n_in,
                              void* d_out, int out_size, void* d_ws, size_t ws_size,
                              hipStream_t stream) {
    const float* feature    = (const float*)d_in[0];
    const int*   src        = (const int*)  d_in[1];
    const int*   dst        = (const int*)  d_in[2];
    const float* sp_dist    = (const float*)d_in[3];
    const int*   anchor_eid = (const int*)  d_in[4];
    // d_in[5] = dists_max: shape-only, numerically unused.
    const float* W_u   = (const float*)d_in[6];
    const float* b_u   = (const float*)d_in[7];
    const float* W_v   = (const float*)d_in[8];
    const float* b_v   = (const float*)d_in[9];
    const float* W_out = (const float*)d_in[10];
    const float* b_out = (const float*)d_in[11];

    const int N = in_sizes[0] / IN_DIM;           // 50000
    const int E = in_sizes[1];                    // 3.2M
    const int M = N * KANCH;

    unsigned char* uq8 = (unsigned char*)d_ws;    // [2][N][32] fp8, 3.2 MB
    size_t uq8_bytes  = (size_t)N * 64;
    size_t vh_off     = (uq8_bytes + 255) & ~(size_t)255;
    __half* vh16      = (__half*)((char*)d_ws + vh_off);   // [2][N][32] fp16, 6.4 MB
    size_t vh_bytes   = (size_t)N * 64 * sizeof(__half);
    size_t packed_off = (vh_off + vh_bytes + 255) & ~(size_t)255;
    size_t meta_off   = (packed_off + (size_t)M * 8 + 255) & ~(size_t)255;
    unsigned long long* packed = (unsigned long long*)((char*)d_ws + packed_off);
    unsigned long long* meta   = (unsigned long long*)((char*)d_ws + meta_off);
    const bool fields_fit = (N < (1 << 17));
    const bool use_packed = fields_fit && (ws_size >= meta_off + (size_t)E * 8);

    float* out_pos    = (float*)d_out;            // [N,K]
    float* out_struct = (float*)d_out + (size_t)N * KANCH;

    const int projBlocks = (N + 63) / 64;         // 782
    const int nblk = (N + 3) / 4;                 // 12500

    if (use_packed) {
        pgnn_merge_kernel<<<dim3((E + 255) / 256), 256, 0, stream>>>(
            src, dst, sp_dist, meta, E);
        // grid G: proj blocks at idx%4!=3, pack blocks at idx%4==3.
        // G - floor stuff: choose G so proj count = projBlocks.
        const int G = (4 * projBlocks + 2) / 3;   // 1043 -> proj 782/783ish
        const int packBlocks = G / 4;             // pack ids 0..packBlocks-1
        pgnn_front_kernel<<<dim3(G), 256, 0, stream>>>(
            feature, W_u, b_u, W_v, b_v, uq8, vh16, anchor_eid, meta, packed,
            N, M, projBlocks, packBlocks);
        pgnn_pass_kernel<0, true><<<dim3(nblk), 256, 0, stream>>>(
            uq8, vh16, src, dst, sp_dist, anchor_eid, packed, W_out,
            b_out, out_pos, out_struct, N, 0);
        pgnn_pass_kernel<0, false><<<dim3(nblk), 256, 0, stream>>>(
            uq8, vh16, src, dst, sp_dist, anchor_eid, packed, W_out,
            b_out, out_pos, out_struct, N, 1);
    } else {
        pgnn_front_kernel<<<dim3(projBlocks), 256, 0, stream>>>(
            feature, W_u, b_u, W_v, b_v, uq8, vh16, anchor_eid, meta, packed,
            N, M, projBlocks, 0 /* all proj */);
        pgnn_pass_kernel<2, true><<<dim3(nblk), 256, 0, stream>>>(
            uq8, vh16, src, dst, sp_dist, anchor_eid, packed, W_out,
            b_out, out_pos, out_struct, N, 0);
        pgnn_pass_kernel<2, false><<<dim3(nblk), 256, 0, stream>>>(
            uq8, vh16, src, dst, sp_dist, anchor_eid, packed, W_out,
            b_out, out_pos, out_struct, N, 1);
    }
}

// Round 23
// 188.995 us; speedup vs baseline: 1.4249x; 1.4249x over previous
//
#include <hip/hip_runtime.h>
#include <hip/hip_fp16.h>
#include <hip/hip_bf16.h>

// PGNN layer for MI355X (gfx950).
//   u = feature @ W_u + b_u ; v = feature @ W_v + b_v       [N,64] each
//   msg[e] = v[dst[e]] + u[src[e]] * sp_dist[e]
//   msgs = relu(msg[anchor_eid]) -> [N,K,64]
//   out_position = msgs @ W_out + b_out  [N,K];  out_structure = mean_k [N,64]
// N=50000, K=64, E=3.2M. d_out = out_position ++ out_structure.
//
// R23 = R22 resubmitted (infra failure, never measured).
// R22 vs R21 (evidence: ALL 4 proj+pack fusion variants fail (102/135/115/
// 162us) -> resource coupling / barrier drains; best = serial. pass2 at
// touch-model floor):
//   - proj rewritten with v_mfma_f32_16x16x32_f16 (fp16 inputs, fp32 acc):
//     64x128 tile, 4 waves x 8 col-frags, K=8x32. W pre-transposed to
//     Wt[128][256] fp16 in the merge launch. ~50us VALU -> ~20us.
//   - phases serial: merge+Wt -> pack -> proj-MFMA -> pass0 -> pass1.
//   - error: +1-2e-4 on v from fp16 rounding; predicted absmax ~5.6e-3.

#define IN_DIM 256
#define OUT_DIM 64
#define KANCH 64

typedef float vfloat4 __attribute__((ext_vector_type(4)));
typedef float vfloat2 __attribute__((ext_vector_type(2)));
typedef _Float16 f16x8 __attribute__((ext_vector_type(8)));
typedef float f32x4 __attribute__((ext_vector_type(4)));

// ---------------- merge + Wt build (one launch) ----------------------------
// Blocks [0, mergeBlocks): meta[i] = src|dst<<17|half(sp)<<34 (ids < 2^17).
// Blocks [mergeBlocks, +16): Wt[c][k] = fp16(c<64 ? Wu[k][c] : Wv[k][c-64]).
__global__ __launch_bounds__(256) void pgnn_merge_kernel(
    const int* __restrict__ src, const int* __restrict__ dst,
    const float* __restrict__ sp, unsigned long long* __restrict__ meta, int E,
    const float* __restrict__ Wu, const float* __restrict__ Wv,
    __half* __restrict__ Wt, int mergeBlocks)
{
    const int tid = threadIdx.x;
    if ((int)blockIdx.x < mergeBlocks) {
        int i = blockIdx.x * 256 + tid;
        if (i >= E) return;
        unsigned long long pk =
              (unsigned long long)(unsigned)__builtin_nontemporal_load(&src[i])
            | ((unsigned long long)(unsigned)__builtin_nontemporal_load(&dst[i]) << 17)
            | ((unsigned long long)__half_as_ushort(
                   __float2half_rn(__builtin_nontemporal_load(&sp[i]))) << 34);
        __builtin_nontemporal_store(pk, &meta[i]);
    } else {
        // 16 blocks x 256 threads x 8 entries = 32768 = 128 cols x 256 k
        int idx = (blockIdx.x - mergeBlocks) * 256 + tid;   // 0..4095
        int c  = idx >> 5;            // 0..127
        int k0 = (idx & 31) * 8;
        #pragma unroll
        for (int j = 0; j < 8; ++j) {
            int k = k0 + j;
            float val = (c < OUT_DIM) ? Wu[k * OUT_DIM + c]
                                      : Wv[k * OUT_DIM + (c - OUT_DIM)];
            Wt[c * IN_DIM + k] = __float2half_rn(val);
        }
    }
}

// ---------------- pack: packed[i] = meta[aeid[i]] --------------------------
__global__ __launch_bounds__(256) void pgnn_pack_kernel(
    const int* __restrict__ aeid, const unsigned long long* __restrict__ meta,
    unsigned long long* __restrict__ packed, int M, int packBlocks)
{
    const int stride = packBlocks * 256;
    int i = blockIdx.x * 256 + threadIdx.x;
    while (i + 7 * stride < M) {
        int e[8];
        #pragma unroll
        for (int b = 0; b < 8; ++b)
            e[b] = __builtin_nontemporal_load(&aeid[i + b * stride]);
        unsigned long long m[8];
        #pragma unroll
        for (int b = 0; b < 8; ++b) m[b] = meta[e[b]];   // PLAIN (L2/L3)
        #pragma unroll
        for (int b = 0; b < 8; ++b)
            __builtin_nontemporal_store(m[b], &packed[i + b * stride]);
        i += 8 * stride;
    }
    for (; i < M; i += stride) {
        int e = __builtin_nontemporal_load(&aeid[i]);
        __builtin_nontemporal_store(meta[e], &packed[i]);
    }
}

// ---------------- proj GEMM via fp16 MFMA ----------------------------------
// C[64 rows][128 cols] per block; 4 waves, wave w owns rows w*16..+15, all
// 128 cols as 8 col-fragments. K-loop 8 steps of 32.
// A-frag: lane holds A[lane&15][(lane>>4)*8 + j]  (16 rows x 32 k)
// B-frag: lane holds B[(lane>>4)*8 + j][lane&15]  (32 k x 16 cols)
// C/D:    col = lane&15, row = (lane>>4)*4 + reg  [m89-verified]
// Outputs: uq8[2][N][32] fp8 e4m3 (u, cols 0..63), vh16[2][N][32] fp16 (v).
__global__ __launch_bounds__(256) void pgnn_proj_mfma_kernel(
    const float* __restrict__ feature,
    const __half* __restrict__ Wt,      // [128][256] fp16
    const float* __restrict__ bu, const float* __restrict__ bv,
    unsigned char* __restrict__ uq8,
    __half* __restrict__ vh16, int N)
{
    __shared__ _Float16 sA[4 * 4 * 16 * 8];   // [wchunk][kb][row16][8]
    __shared__ _Float16 sB[8 * 4 * 16 * 8];   // [cb][kb][col16][8]

    const int tid  = threadIdx.x;
    const int lane = tid & 63, w = tid >> 6;
    const int row0 = blockIdx.x * 64;

    f32x4 acc[8];
    #pragma unroll
    for (int f = 0; f < 8; ++f) acc[f] = (f32x4){0.f, 0.f, 0.f, 0.f};

    const int rowg = tid & 63;        // A-staging: row within tile
    const int kbA  = tid >> 6;        // A-staging: k-block 0..3
    const int grow = row0 + rowg;

    for (int s = 0; s < 8; ++s) {
        const int k0 = s * 32;
        // ---- stage A (64 rows x 32 k), fp32 -> fp16 ----
        {
            _Float16 ah[8];
            if (grow < N) {
                const float* fp = &feature[(size_t)grow * IN_DIM + k0 + kbA * 8];
                float4 f0 = *reinterpret_cast<const float4*>(fp);
                float4 f1 = *reinterpret_cast<const float4*>(fp + 4);
                ah[0] = (_Float16)f0.x; ah[1] = (_Float16)f0.y;
                ah[2] = (_Float16)f0.z; ah[3] = (_Float16)f0.w;
                ah[4] = (_Float16)f1.x; ah[5] = (_Float16)f1.y;
                ah[6] = (_Float16)f1.z; ah[7] = (_Float16)f1.w;
            } else {
                #pragma unroll
                for (int j = 0; j < 8; ++j) ah[j] = (_Float16)0.f;
            }
            *reinterpret_cast<f16x8*>(
                &sA[((rowg >> 4) * 4 + kbA) * 128 + (rowg & 15) * 8]) =
                *reinterpret_cast<f16x8*>(ah);
        }
        // ---- stage B (32 k x 128 cols) from Wt[col][k] ----
        #pragma unroll
        for (int c = 0; c < 2; ++c) {
            int flat = tid + c * 256;          // 0..511
            int f   = flat >> 6;               // col-block 0..7
            int kb  = (flat >> 4) & 3;         // k-block 0..3
            int col = flat & 15;
            const __half* wp = &Wt[(size_t)(f * 16 + col) * IN_DIM + k0 + kb * 8];
            *reinterpret_cast<uint4*>(&sB[((f * 4 + kb) * 16 + col) * 8]) =
                *reinterpret_cast<const uint4*>(wp);
        }
        __syncthreads();

        // ---- MFMA ----
        f16x8 afrag = *reinterpret_cast<f16x8*>(
            &sA[(w * 4 + (lane >> 4)) * 128 + (lane & 15) * 8]);
        #pragma unroll
        for (int f = 0; f < 8; ++f) {
            f16x8 bfrag = *reinterpret_cast<f16x8*>(
                &sB[((f * 4 + (lane >> 4)) * 16 + (lane & 15)) * 8]);
            acc[f] = __builtin_amdgcn_mfma_f32_16x16x32_f16(afrag, bfrag,
                                                            acc[f], 0, 0, 0);
        }
        __syncthreads();
    }

    // ---- epilogue: bias; u -> fp8, v -> fp16 ----
    const int wrow0 = row0 + w * 16;
    const int rbase = wrow0 + ((lane >> 4) << 2);
    const int cl = lane & 15;
    #pragma unroll
    for (int f = 0; f < 4; ++f) {           // u columns 0..63
        const int col = f * 16 + cl;
        const float bias = bu[col];
        const int qs = col >> 5, dim = col & 31;
        #pragma unroll
        for (int reg = 0; reg < 4; ++reg) {
            int row = rbase + reg;
            if (row < N) {
                float val = acc[f][reg] + bias;
                int pk = __builtin_amdgcn_cvt_pk_fp8_f32(val, val, 0, false);
                uq8[((size_t)qs * N + row) * 32 + dim] = (unsigned char)pk;
            }
        }
    }
    #pragma unroll
    for (int f = 4; f < 8; ++f) {           // v columns 64..127
        const int c2 = f * 16 + cl - 64;
        const float bias = bv[c2];
        const int qs = c2 >> 5, dim = c2 & 31;
        #pragma unroll
        for (int reg = 0; reg < 4; ++reg) {
            int row = rbase + reg;
            if (row < N)
                vh16[((size_t)qs * N + row) * 32 + dim] =
                    __float2half_rn(acc[f][reg] + bias);
        }
    }
}

// ---------------- edge pass (u fp8 + v fp16, one slice q) ------------------
// One wave per node, 4 waves/block. lane = (g = lane>>2, j = lane&3).
// Anchor k = i*16+g (i=0..3): u = 8B fp8 octet of row ss, v = 16B fp16 octet
// of row dd. META: 0 = read packed (coalesced), 2 = raw gather (fallback).
// FIRST: plain-store pos + b_out (else atomicAdd).
template<int META, bool FIRST>
__global__ __launch_bounds__(256) void pgnn_pass_kernel(
    const unsigned char* __restrict__ uq8,
    const __half* __restrict__ vh16,
    const int*    __restrict__ src,
    const int*    __restrict__ dst,
    const float*  __restrict__ sp_dist,
    const int*    __restrict__ aeid,
    const unsigned long long* __restrict__ packed,
    const float*  __restrict__ W_out,
    const float*  __restrict__ b_out,
    float* __restrict__ out_pos,     // [N,64]
    float* __restrict__ out_struct,  // [N,64]
    int N, int q)
{
    const int lane = threadIdx.x & 63;
    const int wv   = threadIdx.x >> 6;
    const int n    = blockIdx.x * 4 + wv;
    if (n >= N) return;   // wave-uniform

    __shared__ float posb[4][64];
    float* pb = posb[wv];

    const int j = lane & 3, g = lane >> 2;

    int ms, md; float msp;
    if constexpr (META == 2) {
        const int e = __builtin_nontemporal_load(&aeid[(size_t)n * KANCH + lane]);
        ms = src[e]; md = dst[e]; msp = sp_dist[e];
    } else {
        unsigned long long pk =
            __builtin_nontemporal_load(&packed[(size_t)n * KANCH + lane]);
        unsigned lo = (unsigned)pk, hi = (unsigned)(pk >> 32);
        ms = (int)(lo & 0x1FFFFu);
        md = (int)(((lo >> 17) | (hi << 15)) & 0x1FFFFu);
        msp = __half2float(__ushort_as_half((unsigned short)((hi >> 2) & 0xFFFFu)));
    }

    // W_out dims q*32 + j*8 .. +7
    float w[8];
    {
        const float* Wq = &W_out[q * 32 + j * 8];
        float4 w0 = *reinterpret_cast<const float4*>(Wq);
        float4 w1 = *reinterpret_cast<const float4*>(Wq + 4);
        w[0] = w0.x; w[1] = w0.y; w[2] = w0.z; w[3] = w0.w;
        w[4] = w1.x; w[5] = w1.y; w[6] = w1.z; w[7] = w1.w;
    }

    const unsigned char* Uq = uq8  + (size_t)q * N * 32;
    const __half*        Vq = vh16 + (size_t)q * N * 32;

    float sacc[8];
    #pragma unroll
    for (int jj = 0; jj < 8; ++jj) sacc[jj] = 0.f;

    #pragma unroll
    for (int i = 0; i < 4; ++i) {
        const int k = i * 16 + g;
        const int   ss = __shfl(ms, k);
        const int   dd = __shfl(md, k);
        const float sp = __shfl(msp, k);

        uint2 uu = *reinterpret_cast<const uint2*>(Uq + (size_t)ss * 32 + j * 8);
        uint4 vv = *reinterpret_cast<const uint4*>(
                       reinterpret_cast<const unsigned char*>(Vq) +
                       (size_t)dd * 64 + j * 16);

        float uf[8], vf[8];
        {
            vfloat2 a0 = __builtin_amdgcn_cvt_pk_f32_fp8((int)uu.x, false);
            vfloat2 a1 = __builtin_amdgcn_cvt_pk_f32_fp8((int)uu.x, true);
            vfloat2 a2 = __builtin_amdgcn_cvt_pk_f32_fp8((int)uu.y, false);
            vfloat2 a3 = __builtin_amdgcn_cvt_pk_f32_fp8((int)uu.y, true);
            uf[0] = a0.x; uf[1] = a0.y; uf[2] = a1.x; uf[3] = a1.y;
            uf[4] = a2.x; uf[5] = a2.y; uf[6] = a3.x; uf[7] = a3.y;
        }
        {
            const unsigned* vp = &vv.x;
            #pragma unroll
            for (int t = 0; t < 4; ++t) {
                __half2 h2 = *reinterpret_cast<const __half2*>(&vp[t]);
                float2 f2 = __half22float2(h2);
                vf[2 * t] = f2.x; vf[2 * t + 1] = f2.y;
            }
        }

        float m[8];
        #pragma unroll
        for (int jj = 0; jj < 8; ++jj) {
            m[jj] = fmaxf(fmaf(uf[jj], sp, vf[jj]), 0.f);
            sacc[jj] += m[jj];
        }

        float p = 0.f;
        #pragma unroll
        for (int jj = 0; jj < 8; ++jj) p = fmaf(m[jj], w[jj], p);
        p += __shfl_xor(p, 1);
        p += __shfl_xor(p, 2);          // sum over the 4-lane quad
        if (j == 0) pb[k] = p;
    }
    asm volatile("s_waitcnt lgkmcnt(0)" ::: "memory");

    if constexpr (FIRST) {
        out_pos[(size_t)n * KANCH + lane] = pb[lane] + b_out[0];
    } else {
        atomicAdd(&out_pos[(size_t)n * KANCH + lane], pb[lane]);
    }

    // struct: reduce sacc over the 16 g-groups (lane bits 2..5).
    #pragma unroll
    for (int off = 4; off <= 32; off <<= 1)
        #pragma unroll
        for (int jj = 0; jj < 8; ++jj)
            sacc[jj] += __shfl_xor(sacc[jj], off);

    if (lane < 4) {   // lane j holds dims q*32 + j*8 .. +7
        const float r = 1.f / (float)KANCH;
        float* op = &out_struct[(size_t)n * OUT_DIM + q * 32 + lane * 8];
        vfloat4 s0 = { sacc[0] * r, sacc[1] * r, sacc[2] * r, sacc[3] * r };
        vfloat4 s1 = { sacc[4] * r, sacc[5] * r, sacc[6] * r, sacc[7] * r };
        __builtin_nontemporal_store(s0, reinterpret_cast<vfloat4*>(op));
        __builtin_nontemporal_store(s1, reinterpret_cast<vfloat4*>(op + 4));
    }
}

extern "C" void kernel_launch(void* const* d_in, const int* in_sizes, int n_in,
                              void* d_out, int out_size, void* d_ws, size_t ws_size,
                              hipStream_t stream) {
    const float* feature    = (const float*)d_in[0];
    const int*   src        = (const int*)  d_in[1];
    const int*   dst        = (const int*)  d_in[2];
    const float* sp_dist    = (const float*)d_in[3];
    const int*   anchor_eid = (const int*)  d_in[4];
    // d_in[5] = dists_max: shape-only, numerically unused.
    const float* W_u   = (const float*)d_in[6];
    const float* b_u   = (const float*)d_in[7];
    const float* W_v   = (const float*)d_in[8];
    const float* b_v   = (const float*)d_in[9];
    const float* W_out = (const float*)d_in[10];
    const float* b_out = (const float*)d_in[11];

    const int N = in_sizes[0] / IN_DIM;           // 50000
    const int E = in_sizes[1];                    // 3.2M
    const int M = N * KANCH;

    unsigned char* uq8 = (unsigned char*)d_ws;    // [2][N][32] fp8, 3.2 MB
    size_t uq8_bytes  = (size_t)N * 64;
    size_t vh_off     = (uq8_bytes + 255) & ~(size_t)255;
    __half* vh16      = (__half*)((char*)d_ws + vh_off);   // [2][N][32] fp16
    size_t vh_bytes   = (size_t)N * 64 * sizeof(__half);
    size_t wt_off     = (vh_off + vh_bytes + 255) & ~(size_t)255;
    __half* Wt        = (__half*)((char*)d_ws + wt_off);   // [128][256] fp16
    size_t wt_bytes   = (size_t)128 * IN_DIM * sizeof(__half);
    size_t packed_off = (wt_off + wt_bytes + 255) & ~(size_t)255;
    size_t meta_off   = (packed_off + (size_t)M * 8 + 255) & ~(size_t)255;
    unsigned long long* packed = (unsigned long long*)((char*)d_ws + packed_off);
    unsigned long long* meta   = (unsigned long long*)((char*)d_ws + meta_off);
    const bool fields_fit = (N < (1 << 17));
    const bool use_packed = fields_fit && (ws_size >= meta_off + (size_t)E * 8);

    float* out_pos    = (float*)d_out;            // [N,K]
    float* out_struct = (float*)d_out + (size_t)N * KANCH;

    const int projBlocks = (N + 63) / 64;         // 782
    const int nblk = (N + 3) / 4;                 // 12500

    if (use_packed) {
        const int mergeBlocks = (E + 255) / 256;  // 12500
        pgnn_merge_kernel<<<dim3(mergeBlocks + 16), 256, 0, stream>>>(
            src, dst, sp_dist, meta, E, W_u, W_v, Wt, mergeBlocks);
        const int packBlocks = 1024;
        pgnn_pack_kernel<<<dim3(packBlocks), 256, 0, stream>>>(
            anchor_eid, meta, packed, M, packBlocks);
        pgnn_proj_mfma_kernel<<<dim3(projBlocks), 256, 0, stream>>>(
            feature, Wt, b_u, b_v, uq8, vh16, N);
        pgnn_pass_kernel<0, true><<<dim3(nblk), 256, 0, stream>>>(
            uq8, vh16, src, dst, sp_dist, anchor_eid, packed, W_out,
            b_out, out_pos, out_struct, N, 0);
        pgnn_pass_kernel<0, false><<<dim3(nblk), 256, 0, stream>>>(
            uq8, vh16, src, dst, sp_dist, anchor_eid, packed, W_out,
            b_out, out_pos, out_struct, N, 1);
    } else {
        pgnn_merge_kernel<<<dim3(16), 256, 0, stream>>>(
            src, dst, sp_dist, meta, 0, W_u, W_v, Wt, 0);
        pgnn_proj_mfma_kernel<<<dim3(projBlocks), 256, 0, stream>>>(
            feature, Wt, b_u, b_v, uq8, vh16, N);
        pgnn_pass_kernel<2, true><<<dim3(nblk), 256, 0, stream>>>(
            uq8, vh16, src, dst, sp_dist, anchor_eid, packed, W_out,
            b_out, out_pos, out_struct, N, 0);
        pgnn_pass_kernel<2, false><<<dim3(nblk), 256, 0, stream>>>(
            uq8, vh16, src, dst, sp_dist, anchor_eid, packed, W_out,
            b_out, out_pos, out_struct, N, 1);
    }
}